// Round 1
// baseline (734.159 us; speedup 1.0000x reference)
//
#include <hip/hip_runtime.h>

#define NUM_USERS 25000
#define NUM_ITEMS 25000
#define N_NODES   50000
#define N_EDGES   800000
#define K         64
#define N_QUERY   4096
#define LRELU     0.2f

// out layout: [ xui (4096) | gu (25000 x 256) | gi (25000 x 256) ]
__device__ __forceinline__ size_t node_out_offset(int n) {
    // row base for node n in the gu/gi region (256 floats per row)
    return (size_t)N_QUERY + (size_t)n * 256;   // gu rows then gi rows are contiguous
}

// ---------------------------------------------------------------------------
// init: ego = concat(Gu0, Gi0); also write layer-0 block (cols 0..63) of out
// ---------------------------------------------------------------------------
__global__ __launch_bounds__(256) void init_ego_kernel(
    const float* __restrict__ Gu0, const float* __restrict__ Gi0,
    float* __restrict__ ego, float* __restrict__ out)
{
    int tid = blockIdx.x * 256 + threadIdx.x;      // 0 .. N_NODES*K-1
    if (tid >= N_NODES * K) return;
    int n = tid >> 6;
    int d = tid & 63;
    float v = (n < NUM_USERS) ? Gu0[tid] : Gi0[tid - NUM_USERS * K];
    ego[tid] = v;
    out[node_out_offset(n) + d] = v;               // column block 0 (un-normalized ego0)
}

// ---------------------------------------------------------------------------
// SpMM scatter: side[r] += vals[e] * ego[c]   (one wave per edge, lane = dim)
// ---------------------------------------------------------------------------
__global__ __launch_bounds__(256) void spmm_kernel(
    const int* __restrict__ rows, const int* __restrict__ cols,
    const float* __restrict__ vals, const float* __restrict__ ego,
    float* __restrict__ side)
{
    int tid = blockIdx.x * 256 + threadIdx.x;      // 0 .. N_EDGES*64-1
    int e = tid >> 6;
    if (e >= N_EDGES) return;
    int d = tid & 63;
    float v = vals[e];                              // wave-uniform (broadcast)
    int c = cols[e];
    int r = rows[e];
    atomicAdd(&side[r * K + d], v * ego[c * K + d]);
}

// ---------------------------------------------------------------------------
// fused layer: sum_emb / bi_emb GEMVs + bias + leaky_relu + add + L2-norm
// one wave per node; lane = output dim; W matrices staged in LDS
// grid = N_NODES/4 blocks of 256 (exactly covers 50000 nodes)
// ---------------------------------------------------------------------------
__global__ __launch_bounds__(256) void layer_fused_kernel(
    const float* __restrict__ side, float* __restrict__ ego,
    const float* __restrict__ Wgc, const float* __restrict__ bgc,
    const float* __restrict__ Wbi, const float* __restrict__ bbi,
    float* __restrict__ out, int layer_k)
{
    __shared__ float s_wgc[K * K];
    __shared__ float s_wbi[K * K];
    __shared__ float s_srow[4][K];
    __shared__ float s_esrow[4][K];

    int t = threadIdx.x;
    for (int i = t; i < K * K; i += 256) {
        s_wgc[i] = Wgc[i];
        s_wbi[i] = Wbi[i];
    }

    int wave = t >> 6;
    int lane = t & 63;
    int node = blockIdx.x * 4 + wave;              // grid sized so node < N_NODES always

    float s = side[node * K + lane];
    float e = ego[node * K + lane];
    s_srow[wave][lane]  = s;
    s_esrow[wave][lane] = e * s;
    __syncthreads();

    float accg = 0.f, accb = 0.f;
    #pragma unroll
    for (int j = 0; j < K; ++j) {
        float sj  = s_srow[wave][j];               // LDS broadcast (conflict-free)
        float esj = s_esrow[wave][j];
        accg = fmaf(sj,  s_wgc[j * K + lane], accg);
        accb = fmaf(esj, s_wbi[j * K + lane], accb);
    }
    accg += bgc[lane];
    accb += bbi[lane];
    accg = (accg > 0.f) ? accg : LRELU * accg;
    accb = (accb > 0.f) ? accb : LRELU * accb;

    float en = accg + accb;
    ego[node * K + lane] = en;                     // un-normalized ego for next layer

    // row L2 norm across the 64 lanes
    float ss = en * en;
    #pragma unroll
    for (int off = 32; off; off >>= 1) ss += __shfl_xor(ss, off);
    float nv = en * rsqrtf(fmaxf(ss, 1e-12f));

    out[node_out_offset(node) + (size_t)(layer_k + 1) * K + lane] = nv;
}

// ---------------------------------------------------------------------------
// readout: xui[i] = dot(gu[user[i]], gi[item[i]])  (256-dim), one wave per pair
// ---------------------------------------------------------------------------
__global__ __launch_bounds__(256) void xui_kernel(
    const int* __restrict__ user, const int* __restrict__ item,
    float* __restrict__ out)
{
    int idx = blockIdx.x * 4 + (threadIdx.x >> 6);
    if (idx >= N_QUERY) return;
    int lane = threadIdx.x & 63;
    int u  = user[idx];
    int it = item[idx];
    const float4* gu = (const float4*)(out + (size_t)N_QUERY + (size_t)u * 256);
    const float4* gi = (const float4*)(out + (size_t)N_QUERY + (size_t)NUM_ITEMS * 256
                                           + (size_t)it * 256);
    float4 a = gu[lane];
    float4 b = gi[lane];
    float d = a.x * b.x + a.y * b.y + a.z * b.z + a.w * b.w;
    #pragma unroll
    for (int off = 32; off; off >>= 1) d += __shfl_xor(d, off);
    if (lane == 0) out[idx] = d;
}

extern "C" void kernel_launch(void* const* d_in, const int* in_sizes, int n_in,
                              void* d_out, int out_size, void* d_ws, size_t ws_size,
                              hipStream_t stream)
{
    const int*   adj_rows = (const int*)  d_in[0];
    const int*   adj_cols = (const int*)  d_in[1];
    const float* adj_vals = (const float*)d_in[2];
    const float* Gu0      = (const float*)d_in[3];
    const float* Gi0      = (const float*)d_in[4];
    const float* W_gc     = (const float*)d_in[5];   // [3][64][64]
    const float* b_gc     = (const float*)d_in[6];   // [3][64]
    const float* W_bi     = (const float*)d_in[7];
    const float* b_bi     = (const float*)d_in[8];
    const int*   user     = (const int*)  d_in[9];
    const int*   item     = (const int*)  d_in[10];

    float* out  = (float*)d_out;
    float* side = (float*)d_ws;                          // 50000*64 f32 = 12.8 MB
    float* ego  = (float*)d_ws + (size_t)N_NODES * K;    // 12.8 MB

    // init ego + layer-0 output block
    {
        int total = N_NODES * K;
        init_ego_kernel<<<(total + 255) / 256, 256, 0, stream>>>(Gu0, Gi0, ego, out);
    }

    for (int k = 0; k < 3; ++k) {
        hipMemsetAsync(side, 0, (size_t)N_NODES * K * sizeof(float), stream);
        {
            int total = N_EDGES * K;                     // 51.2M threads, 1 per (edge,dim)
            spmm_kernel<<<(total + 255) / 256, 256, 0, stream>>>(
                adj_rows, adj_cols, adj_vals, ego, side);
        }
        layer_fused_kernel<<<N_NODES / 4, 256, 0, stream>>>(
            side, ego,
            W_gc + (size_t)k * K * K, b_gc + (size_t)k * K,
            W_bi + (size_t)k * K * K, b_bi + (size_t)k * K,
            out, k);
    }

    xui_kernel<<<N_QUERY / 4, 256, 0, stream>>>(user, item, out);
}

// Round 2
// 724.221 us; speedup vs baseline: 1.0137x; 1.0137x over previous
//
#include <hip/hip_runtime.h>

#define NUM_USERS 25000
#define NUM_ITEMS 25000
#define N_NODES   50000
#define N_EDGES   800000
#define K         64
#define N_QUERY   4096
#define LRELU     0.2f

// out layout: [ xui (4096) | gu (25000 x 256) | gi (25000 x 256) ]
__device__ __forceinline__ size_t node_out_offset(int n) {
    return (size_t)N_QUERY + (size_t)n * 256;
}

__global__ __launch_bounds__(256) void init_ego_kernel(
    const float* __restrict__ Gu0, const float* __restrict__ Gi0,
    float* __restrict__ ego, float* __restrict__ out)
{
    int tid = blockIdx.x * 256 + threadIdx.x;
    if (tid >= N_NODES * K) return;
    int n = tid >> 6;
    int d = tid & 63;
    float v = (n < NUM_USERS) ? Gu0[tid] : Gi0[tid - NUM_USERS * K];
    ego[tid] = v;
    out[node_out_offset(n) + d] = v;
}

__global__ __launch_bounds__(256) void count_kernel(
    const int* __restrict__ rows, int* __restrict__ counts)
{
    int e = blockIdx.x * 256 + threadIdx.x;
    if (e >= N_EDGES) return;
    atomicAdd(&counts[rows[e]], 1);
}

// exclusive scan over counts -> offs and cursor. counts and cursor MAY alias:
// each thread's chunk is buffered into registers before any write.
__global__ __launch_bounds__(1024) void scan_kernel(
    const int* __restrict__ counts, int* __restrict__ offs, int* __restrict__ cursor)
{
    __shared__ int partial[1024];
    const int CH = (N_NODES + 1023) / 1024;   // 49
    int t = threadIdx.x;
    int base = t * CH;
    int buf[CH];
    int s = 0;
    for (int i = 0; i < CH; ++i) {
        int idx = base + i;
        buf[i] = (idx < N_NODES) ? counts[idx] : 0;
        s += buf[i];
    }
    partial[t] = s;
    __syncthreads();
    for (int off = 1; off < 1024; off <<= 1) {
        int v = (t >= off) ? partial[t - off] : 0;
        __syncthreads();
        partial[t] += v;
        __syncthreads();
    }
    int excl = (t == 0) ? 0 : partial[t - 1];
    for (int i = 0; i < CH; ++i) {
        int idx = base + i;
        if (idx < N_NODES) {
            offs[idx]   = excl;
            cursor[idx] = excl;
            excl += buf[i];
        }
    }
    if (t == 1023) offs[N_NODES] = excl;
}

__global__ __launch_bounds__(256) void scatter_kernel(
    const int* __restrict__ rows, const int* __restrict__ cols,
    const float* __restrict__ vals, int* __restrict__ cursor,
    int* __restrict__ csr_col, float* __restrict__ csr_val)
{
    int e = blockIdx.x * 256 + threadIdx.x;
    if (e >= N_EDGES) return;
    int r = rows[e];
    int pos = atomicAdd(&cursor[r], 1);
    csr_col[pos] = cols[e];
    csr_val[pos] = vals[e];
}

// fused layer: CSR gather (no atomics) + both GEMVs + bias + lrelu + L2 norm
__global__ __launch_bounds__(256) void layer_kernel(
    const int* __restrict__ offs, const int* __restrict__ csr_col,
    const float* __restrict__ csr_val,
    const float* __restrict__ ego_in, float* __restrict__ ego_out,
    const float* __restrict__ Wgc, const float* __restrict__ bgc,
    const float* __restrict__ Wbi, const float* __restrict__ bbi,
    float* __restrict__ out, int layer_k)
{
    __shared__ float s_wgc[K * K];
    __shared__ float s_wbi[K * K];
    __shared__ float s_srow[4][K];
    __shared__ float s_esrow[4][K];

    int t = threadIdx.x;
    for (int i = t; i < K * K; i += 256) {
        s_wgc[i] = Wgc[i];
        s_wbi[i] = Wbi[i];
    }

    int wave = t >> 6;
    int lane = t & 63;
    int node = blockIdx.x * 4 + wave;

    int beg = offs[node];
    int end = offs[node + 1];
    float acc = 0.f;
    for (int j = beg; j < end; ++j) {
        int   c = csr_col[j];
        float v = csr_val[j];
        acc = fmaf(v, ego_in[(size_t)c * K + lane], acc);
    }

    float e = ego_in[(size_t)node * K + lane];
    s_srow[wave][lane]  = acc;
    s_esrow[wave][lane] = e * acc;
    __syncthreads();

    float accg = 0.f, accb = 0.f;
    #pragma unroll
    for (int j = 0; j < K; ++j) {
        float sj  = s_srow[wave][j];
        float esj = s_esrow[wave][j];
        accg = fmaf(sj,  s_wgc[j * K + lane], accg);
        accb = fmaf(esj, s_wbi[j * K + lane], accb);
    }
    accg += bgc[lane];
    accb += bbi[lane];
    accg = (accg > 0.f) ? accg : LRELU * accg;
    accb = (accb > 0.f) ? accb : LRELU * accb;

    float en = accg + accb;
    ego_out[(size_t)node * K + lane] = en;

    float ss = en * en;
    #pragma unroll
    for (int off = 32; off; off >>= 1) ss += __shfl_xor(ss, off);
    float nv = en * rsqrtf(fmaxf(ss, 1e-12f));

    out[node_out_offset(node) + (size_t)(layer_k + 1) * K + lane] = nv;
}

__global__ __launch_bounds__(256) void xui_kernel(
    const int* __restrict__ user, const int* __restrict__ item,
    float* __restrict__ out)
{
    int idx = blockIdx.x * 4 + (threadIdx.x >> 6);
    if (idx >= N_QUERY) return;
    int lane = threadIdx.x & 63;
    int u  = user[idx];
    int it = item[idx];
    const float4* gu = (const float4*)(out + (size_t)N_QUERY + (size_t)u * 256);
    const float4* gi = (const float4*)(out + (size_t)N_QUERY + (size_t)NUM_ITEMS * 256
                                           + (size_t)it * 256);
    float4 a = gu[lane];
    float4 b = gi[lane];
    float d = a.x * b.x + a.y * b.y + a.z * b.z + a.w * b.w;
    #pragma unroll
    for (int off = 32; off; off >>= 1) d += __shfl_xor(d, off);
    if (lane == 0) out[idx] = d;
}

extern "C" void kernel_launch(void* const* d_in, const int* in_sizes, int n_in,
                              void* d_out, int out_size, void* d_ws, size_t ws_size,
                              hipStream_t stream)
{
    const int*   adj_rows = (const int*)  d_in[0];
    const int*   adj_cols = (const int*)  d_in[1];
    const float* adj_vals = (const float*)d_in[2];
    const float* Gu0      = (const float*)d_in[3];
    const float* Gi0      = (const float*)d_in[4];
    const float* W_gc     = (const float*)d_in[5];
    const float* b_gc     = (const float*)d_in[6];
    const float* W_bi     = (const float*)d_in[7];
    const float* b_bi     = (const float*)d_in[8];
    const int*   user     = (const int*)  d_in[9];
    const int*   item     = (const int*)  d_in[10];

    float* out = (float*)d_out;

    // workspace layout (~32.4 MB total)
    float* egoA    = (float*)d_ws;
    float* egoB    = egoA + (size_t)N_NODES * K;
    float* csr_val = egoB + (size_t)N_NODES * K;
    int*   csr_col = (int*)(csr_val + N_EDGES);
    int*   offs    = csr_col + N_EDGES;           // N_NODES+1 ints
    int*   cursor  = offs + N_NODES + 1;          // N_NODES+1 ints (doubles as counts)

    // ---- CSR build ----
    hipMemsetAsync(cursor, 0, (N_NODES + 1) * sizeof(int), stream);
    count_kernel<<<(N_EDGES + 255) / 256, 256, 0, stream>>>(adj_rows, cursor);
    scan_kernel<<<1, 1024, 0, stream>>>(cursor, offs, cursor);
    scatter_kernel<<<(N_EDGES + 255) / 256, 256, 0, stream>>>(
        adj_rows, adj_cols, adj_vals, cursor, csr_col, csr_val);

    // ---- init ego + layer-0 output block ----
    init_ego_kernel<<<(N_NODES * K + 255) / 256, 256, 0, stream>>>(Gu0, Gi0, egoA, out);

    // ---- 3 fused layers, ping-pong ego ----
    float* ei = egoA;
    float* eo = egoB;
    for (int k = 0; k < 3; ++k) {
        layer_kernel<<<N_NODES / 4, 256, 0, stream>>>(
            offs, csr_col, csr_val, ei, eo,
            W_gc + (size_t)k * K * K, b_gc + (size_t)k * K,
            W_bi + (size_t)k * K * K, b_bi + (size_t)k * K,
            out, k);
        float* tmp = ei; ei = eo; eo = tmp;
    }

    xui_kernel<<<N_QUERY / 4, 256, 0, stream>>>(user, item, out);
}

// Round 3
// 433.819 us; speedup vs baseline: 1.6923x; 1.6694x over previous
//
#include <hip/hip_runtime.h>

#define NUM_USERS 25000
#define NUM_ITEMS 25000
#define N_NODES   50000
#define N_EDGES   800000
#define K         64
#define N_QUERY   4096
#define LRELU     0.2f

// out layout: [ xui (4096) | gu (25000 x 256) | gi (25000 x 256) ]
__device__ __forceinline__ size_t node_out_offset(int n) {
    return (size_t)N_QUERY + (size_t)n * 256;
}

__global__ __launch_bounds__(256) void init_ego_kernel(
    const float* __restrict__ Gu0, const float* __restrict__ Gi0,
    float* __restrict__ ego, float* __restrict__ out)
{
    int tid = blockIdx.x * 256 + threadIdx.x;
    if (tid >= N_NODES * K) return;
    int n = tid >> 6;
    int d = tid & 63;
    float v = (n < NUM_USERS) ? Gu0[tid] : Gi0[tid - NUM_USERS * K];
    ego[tid] = v;
    out[node_out_offset(n) + d] = v;
}

__global__ __launch_bounds__(256) void count_kernel(
    const int* __restrict__ rows, int* __restrict__ counts)
{
    int e = blockIdx.x * 256 + threadIdx.x;
    if (e >= N_EDGES) return;
    atomicAdd(&counts[rows[e]], 1);
}

// exclusive scan over counts -> offs and cursor. counts and cursor MAY alias:
// each thread's chunk is buffered into registers before any write.
__global__ __launch_bounds__(1024) void scan_kernel(
    const int* __restrict__ counts, int* __restrict__ offs, int* __restrict__ cursor)
{
    __shared__ int partial[1024];
    const int CH = (N_NODES + 1023) / 1024;   // 49
    int t = threadIdx.x;
    int base = t * CH;
    int buf[CH];
    int s = 0;
    for (int i = 0; i < CH; ++i) {
        int idx = base + i;
        buf[i] = (idx < N_NODES) ? counts[idx] : 0;
        s += buf[i];
    }
    partial[t] = s;
    __syncthreads();
    for (int off = 1; off < 1024; off <<= 1) {
        int v = (t >= off) ? partial[t - off] : 0;
        __syncthreads();
        partial[t] += v;
        __syncthreads();
    }
    int excl = (t == 0) ? 0 : partial[t - 1];
    for (int i = 0; i < CH; ++i) {
        int idx = base + i;
        if (idx < N_NODES) {
            offs[idx]   = excl;
            cursor[idx] = excl;
            excl += buf[i];
        }
    }
    if (t == 1023) offs[N_NODES] = excl;
}

__global__ __launch_bounds__(256) void scatter_kernel(
    const int* __restrict__ rows, const int* __restrict__ cols,
    const float* __restrict__ vals, int* __restrict__ cursor,
    int* __restrict__ csr_col, float* __restrict__ csr_val)
{
    int e = blockIdx.x * 256 + threadIdx.x;
    if (e >= N_EDGES) return;
    int r = rows[e];
    int pos = atomicAdd(&cursor[r], 1);
    csr_col[pos] = cols[e];
    csr_val[pos] = vals[e];
}

// ---------------------------------------------------------------------------
// fused layer: CSR gather (batched, 8 outstanding row-gathers) + both GEMVs
// + bias + lrelu + L2 norm.  512 threads = 8 waves = 8 nodes per block.
// grid = 50000/8 = 6250 blocks exactly.
// ---------------------------------------------------------------------------
__global__ __launch_bounds__(512) void layer_kernel(
    const int* __restrict__ offs, const int* __restrict__ csr_col,
    const float* __restrict__ csr_val,
    const float* __restrict__ ego_in, float* __restrict__ ego_out,
    const float* __restrict__ Wgc, const float* __restrict__ bgc,
    const float* __restrict__ Wbi, const float* __restrict__ bbi,
    float* __restrict__ out, int layer_k)
{
    __shared__ float s_wgc[K * K];
    __shared__ float s_wbi[K * K];
    __shared__ float s_srow[8][K];
    __shared__ float s_esrow[8][K];

    int t = threadIdx.x;
    for (int i = t; i < K * K; i += 512) {
        s_wgc[i] = Wgc[i];
        s_wbi[i] = Wbi[i];
    }

    int wave = t >> 6;                 // 0..7
    int lane = t & 63;
    int node = blockIdx.x * 8 + wave;  // < 50000 always

    int beg = offs[node];
    int end = offs[node + 1];
    float acc = 0.f;
    int j = beg;

    // 8-deep batched gather: all 8 row loads independent & in flight together
    for (; j + 8 <= end; j += 8) {
        int   cc[8];
        float vv[8];
        #pragma unroll
        for (int u = 0; u < 8; ++u) { cc[u] = csr_col[j + u]; vv[u] = csr_val[j + u]; }
        float gg[8];
        #pragma unroll
        for (int u = 0; u < 8; ++u) gg[u] = ego_in[((size_t)cc[u] << 6) + lane];
        #pragma unroll
        for (int u = 0; u < 8; ++u) acc = fmaf(vv[u], gg[u], acc);
    }
    // 4-deep tail
    for (; j + 4 <= end; j += 4) {
        int   cc[4];
        float vv[4];
        #pragma unroll
        for (int u = 0; u < 4; ++u) { cc[u] = csr_col[j + u]; vv[u] = csr_val[j + u]; }
        float gg[4];
        #pragma unroll
        for (int u = 0; u < 4; ++u) gg[u] = ego_in[((size_t)cc[u] << 6) + lane];
        #pragma unroll
        for (int u = 0; u < 4; ++u) acc = fmaf(vv[u], gg[u], acc);
    }
    // scalar tail (<=3)
    for (; j < end; ++j)
        acc = fmaf(csr_val[j], ego_in[((size_t)csr_col[j] << 6) + lane], acc);

    float e = ego_in[((size_t)node << 6) + lane];
    s_srow[wave][lane]  = acc;
    s_esrow[wave][lane] = e * acc;
    __syncthreads();

    float accg = 0.f, accb = 0.f;
    #pragma unroll
    for (int jj = 0; jj < K; ++jj) {
        float sj  = s_srow[wave][jj];              // LDS broadcast (conflict-free)
        float esj = s_esrow[wave][jj];
        accg = fmaf(sj,  s_wgc[jj * K + lane], accg);
        accb = fmaf(esj, s_wbi[jj * K + lane], accb);
    }
    accg += bgc[lane];
    accb += bbi[lane];
    accg = (accg > 0.f) ? accg : LRELU * accg;
    accb = (accb > 0.f) ? accb : LRELU * accb;

    float en = accg + accb;
    ego_out[((size_t)node << 6) + lane] = en;

    float ss = en * en;
    #pragma unroll
    for (int off = 32; off; off >>= 1) ss += __shfl_xor(ss, off);
    float nv = en * rsqrtf(fmaxf(ss, 1e-12f));

    out[node_out_offset(node) + (size_t)(layer_k + 1) * K + lane] = nv;
}

__global__ __launch_bounds__(256) void xui_kernel(
    const int* __restrict__ user, const int* __restrict__ item,
    float* __restrict__ out)
{
    int idx = blockIdx.x * 4 + (threadIdx.x >> 6);
    if (idx >= N_QUERY) return;
    int lane = threadIdx.x & 63;
    int u  = user[idx];
    int it = item[idx];
    const float4* gu = (const float4*)(out + (size_t)N_QUERY + (size_t)u * 256);
    const float4* gi = (const float4*)(out + (size_t)N_QUERY + (size_t)NUM_ITEMS * 256
                                           + (size_t)it * 256);
    float4 a = gu[lane];
    float4 b = gi[lane];
    float d = a.x * b.x + a.y * b.y + a.z * b.z + a.w * b.w;
    #pragma unroll
    for (int off = 32; off; off >>= 1) d += __shfl_xor(d, off);
    if (lane == 0) out[idx] = d;
}

extern "C" void kernel_launch(void* const* d_in, const int* in_sizes, int n_in,
                              void* d_out, int out_size, void* d_ws, size_t ws_size,
                              hipStream_t stream)
{
    const int*   adj_rows = (const int*)  d_in[0];
    const int*   adj_cols = (const int*)  d_in[1];
    const float* adj_vals = (const float*)d_in[2];
    const float* Gu0      = (const float*)d_in[3];
    const float* Gi0      = (const float*)d_in[4];
    const float* W_gc     = (const float*)d_in[5];
    const float* b_gc     = (const float*)d_in[6];
    const float* W_bi     = (const float*)d_in[7];
    const float* b_bi     = (const float*)d_in[8];
    const int*   user     = (const int*)  d_in[9];
    const int*   item     = (const int*)  d_in[10];

    float* out = (float*)d_out;

    // workspace layout (~32.4 MB total)
    float* egoA    = (float*)d_ws;
    float* egoB    = egoA + (size_t)N_NODES * K;
    float* csr_val = egoB + (size_t)N_NODES * K;
    int*   csr_col = (int*)(csr_val + N_EDGES);
    int*   offs    = csr_col + N_EDGES;           // N_NODES+1 ints
    int*   cursor  = offs + N_NODES + 1;          // N_NODES+1 ints (doubles as counts)

    // ---- CSR build ----
    hipMemsetAsync(cursor, 0, (N_NODES + 1) * sizeof(int), stream);
    count_kernel<<<(N_EDGES + 255) / 256, 256, 0, stream>>>(adj_rows, cursor);
    scan_kernel<<<1, 1024, 0, stream>>>(cursor, offs, cursor);
    scatter_kernel<<<(N_EDGES + 255) / 256, 256, 0, stream>>>(
        adj_rows, adj_cols, adj_vals, cursor, csr_col, csr_val);

    // ---- init ego + layer-0 output block ----
    init_ego_kernel<<<(N_NODES * K + 255) / 256, 256, 0, stream>>>(Gu0, Gi0, egoA, out);

    // ---- 3 fused layers, ping-pong ego ----
    float* ei = egoA;
    float* eo = egoB;
    for (int k = 0; k < 3; ++k) {
        layer_kernel<<<N_NODES / 8, 512, 0, stream>>>(
            offs, csr_col, csr_val, ei, eo,
            W_gc + (size_t)k * K * K, b_gc + (size_t)k * K,
            W_bi + (size_t)k * K * K, b_bi + (size_t)k * K,
            out, k);
        float* tmp = ei; ei = eo; eo = tmp;
    }

    xui_kernel<<<N_QUERY / 4, 256, 0, stream>>>(user, item, out);
}

// Round 4
// 349.733 us; speedup vs baseline: 2.0992x; 1.2404x over previous
//
#include <hip/hip_runtime.h>

#define NUM_USERS 25000
#define NUM_ITEMS 25000
#define N_NODES   50000
#define N_EDGES   800000
#define K         64
#define N_QUERY   4096
#define LRELU     0.2f

#define NCHUNK 256
#define CHSZ   196          // 256*196 = 50176 >= 50000

// out layout: [ xui (4096) | gu (25000 x 256) | gi (25000 x 256) ]
__device__ __forceinline__ size_t node_out_offset(int n) {
    return (size_t)N_QUERY + (size_t)n * 256;
}

// ---------------------------------------------------------------------------
// init: ego = concat(Gu0, Gi0); also write layer-0 block (cols 0..63) of out
// ---------------------------------------------------------------------------
__global__ __launch_bounds__(256) void init_ego_kernel(
    const float* __restrict__ Gu0, const float* __restrict__ Gi0,
    float* __restrict__ ego, float* __restrict__ out)
{
    int tid = blockIdx.x * 256 + threadIdx.x;
    if (tid >= N_NODES * K) return;
    int n = tid >> 6;
    int d = tid & 63;
    float v = (n < NUM_USERS) ? Gu0[tid] : Gi0[tid - NUM_USERS * K];
    ego[tid] = v;
    out[node_out_offset(n) + d] = v;
}

// ---------------------------------------------------------------------------
// CSR build: histogram
// ---------------------------------------------------------------------------
__global__ __launch_bounds__(256) void count_kernel(
    const int* __restrict__ rows, int* __restrict__ counts)
{
    int e = blockIdx.x * 256 + threadIdx.x;
    if (e >= N_EDGES) return;
    atomicAdd(&counts[rows[e]], 1);
}

// S1: per-chunk sums (chunk b = counts[b*CHSZ .. b*CHSZ+CHSZ))
__global__ __launch_bounds__(256) void s1_kernel(
    const int* __restrict__ counts, int* __restrict__ bsum)
{
    __shared__ int red[256];
    int b = blockIdx.x, t = threadIdx.x;
    int idx = b * CHSZ + t;
    int v = (t < CHSZ && idx < N_NODES) ? counts[idx] : 0;
    red[t] = v;
    __syncthreads();
    for (int off = 128; off; off >>= 1) {
        if (t < off) red[t] += red[t + off];
        __syncthreads();
    }
    if (t == 0) bsum[b] = red[0];
}

// S2: exclusive scan of the 256 chunk sums (single block)
__global__ __launch_bounds__(256) void s2_kernel(int* __restrict__ bsum)
{
    __shared__ int sh[256];
    int t = threadIdx.x;
    sh[t] = bsum[t];
    __syncthreads();
    for (int off = 1; off < 256; off <<= 1) {
        int v = (t >= off) ? sh[t - off] : 0;
        __syncthreads();
        sh[t] += v;
        __syncthreads();
    }
    bsum[t] = (t == 0) ? 0 : sh[t - 1];
}

// S3: per-chunk exclusive scan + base -> offs, cursor.
// cursor MAY alias counts: each thread reads only its own element before any
// write, block ranges are disjoint, and the scan itself runs in LDS.
__global__ __launch_bounds__(256) void s3_kernel(
    const int* __restrict__ counts, const int* __restrict__ bsum,
    int* __restrict__ offs, int* __restrict__ cursor)
{
    __shared__ int sh[256];
    int b = blockIdx.x, t = threadIdx.x;
    int idx = b * CHSZ + t;
    int v = (t < CHSZ && idx < N_NODES) ? counts[idx] : 0;
    sh[t] = v;
    __syncthreads();
    for (int off = 1; off < 256; off <<= 1) {
        int x = (t >= off) ? sh[t - off] : 0;
        __syncthreads();
        sh[t] += x;
        __syncthreads();
    }
    int excl = bsum[b] + sh[t] - v;
    if (t < CHSZ && idx < N_NODES) {
        offs[idx]   = excl;
        cursor[idx] = excl;
    }
    if (b == 0 && t == 0) offs[N_NODES] = N_EDGES;
}

// scatter edges into row-sorted order, packed (col, val)
__global__ __launch_bounds__(256) void scatter_kernel(
    const int* __restrict__ rows, const int* __restrict__ cols,
    const float* __restrict__ vals, int* __restrict__ cursor,
    int2* __restrict__ csr_cv)
{
    int e = blockIdx.x * 256 + threadIdx.x;
    if (e >= N_EDGES) return;
    int r = rows[e];
    int pos = atomicAdd(&cursor[r], 1);
    csr_cv[pos] = make_int2(cols[e], __float_as_int(vals[e]));
}

// ---------------------------------------------------------------------------
// gather: side[n][lane] = sum_e val_e * ego[col_e][lane]. No LDS -> high
// occupancy; 12-deep ILP batches of independent row gathers.
// 512 threads = 8 waves = 8 nodes/block; grid 6250.
// ---------------------------------------------------------------------------
__global__ __launch_bounds__(512, 8) void gather_kernel(
    const int* __restrict__ offs, const int2* __restrict__ csr_cv,
    const float* __restrict__ ego, float* __restrict__ side)
{
    int t = threadIdx.x;
    int wave = t >> 6;
    int lane = t & 63;
    int node = blockIdx.x * 8 + wave;

    int beg = offs[node];
    int end = offs[node + 1];
    float acc = 0.f;
    int j = beg;

    for (; j + 12 <= end; j += 12) {
        int2 cv[12];
        #pragma unroll
        for (int u = 0; u < 12; ++u) cv[u] = csr_cv[j + u];
        float gg[12];
        #pragma unroll
        for (int u = 0; u < 12; ++u) gg[u] = ego[((size_t)cv[u].x << 6) + lane];
        #pragma unroll
        for (int u = 0; u < 12; ++u) acc = fmaf(__int_as_float(cv[u].y), gg[u], acc);
    }
    for (; j + 4 <= end; j += 4) {
        int2 cv[4];
        #pragma unroll
        for (int u = 0; u < 4; ++u) cv[u] = csr_cv[j + u];
        float gg[4];
        #pragma unroll
        for (int u = 0; u < 4; ++u) gg[u] = ego[((size_t)cv[u].x << 6) + lane];
        #pragma unroll
        for (int u = 0; u < 4; ++u) acc = fmaf(__int_as_float(cv[u].y), gg[u], acc);
    }
    for (; j < end; ++j) {
        int2 cv = csr_cv[j];
        acc = fmaf(__int_as_float(cv.y), ego[((size_t)cv.x << 6) + lane], acc);
    }

    side[((size_t)node << 6) + lane] = acc;
}

// ---------------------------------------------------------------------------
// transform: both GEMVs + bias + lrelu + add + L2 norm.
// Weights in VGPRs (reused across 16 nodes/wave); side+ego rows staged in LDS,
// read as uniform (broadcast) float4 — conflict-free, ~32 LDS reads per node.
// ego is updated IN PLACE (each block touches only its own 64 rows).
// block = 256 threads (4 waves), 64 nodes/block, grid 782.
// ---------------------------------------------------------------------------
__global__ __launch_bounds__(256, 3) void transform_kernel(
    const float* __restrict__ side, float* __restrict__ ego,
    const float* __restrict__ Wgc, const float* __restrict__ bgc,
    const float* __restrict__ Wbi, const float* __restrict__ bbi,
    float* __restrict__ out, int layer_k)
{
    __shared__ float s_s[64 * 64];   // side rows, 16 KB
    __shared__ float s_e[64 * 64];   // ego rows, 16 KB

    int t = threadIdx.x, wave = t >> 6, lane = t & 63;
    int base = blockIdx.x * 64;

    // per-lane weight columns, both matrices interleaved: w2[j] = (Wgc[j][lane], Wbi[j][lane])
    float2 w2[64];
    #pragma unroll
    for (int j = 0; j < 64; ++j)
        w2[j] = make_float2(Wgc[j * 64 + lane], Wbi[j * 64 + lane]);
    float bg = bgc[lane], bb = bbi[lane];

    // stage this block's 64 side-rows and ego-rows (coalesced float4)
    {
        const float4* gs = (const float4*)(side + (size_t)base * 64);
        const float4* ge = (const float4*)(ego  + (size_t)base * 64);
        float4* ls = (float4*)s_s;
        float4* le = (float4*)s_e;
        int lim4 = (N_NODES - base < 64 ? N_NODES - base : 64) * 16;
        for (int i = t; i < 64 * 16; i += 256) {
            if (i < lim4) { ls[i] = gs[i]; le[i] = ge[i]; }
        }
    }
    __syncthreads();

    for (int nn = 0; nn < 16; ++nn) {
        int ln = wave * 16 + nn;
        int node = base + ln;
        if (node >= N_NODES) break;
        const float4* s4p = (const float4*)&s_s[ln * 64];
        const float4* e4p = (const float4*)&s_e[ln * 64];
        float accg = 0.f, accb = 0.f;
        #pragma unroll
        for (int q = 0; q < 16; ++q) {
            float4 s4 = s4p[q];            // uniform broadcast read
            float4 e4 = e4p[q];
            accg = fmaf(s4.x, w2[4*q+0].x, accg); accb = fmaf(e4.x*s4.x, w2[4*q+0].y, accb);
            accg = fmaf(s4.y, w2[4*q+1].x, accg); accb = fmaf(e4.y*s4.y, w2[4*q+1].y, accb);
            accg = fmaf(s4.z, w2[4*q+2].x, accg); accb = fmaf(e4.z*s4.z, w2[4*q+2].y, accb);
            accg = fmaf(s4.w, w2[4*q+3].x, accg); accb = fmaf(e4.w*s4.w, w2[4*q+3].y, accb);
        }
        accg += bg; accb += bb;
        accg = (accg > 0.f) ? accg : LRELU * accg;
        accb = (accb > 0.f) ? accb : LRELU * accb;
        float en = accg + accb;
        ego[((size_t)node << 6) + lane] = en;

        float ss = en * en;
        #pragma unroll
        for (int off = 32; off; off >>= 1) ss += __shfl_xor(ss, off);
        float nv = en * rsqrtf(fmaxf(ss, 1e-12f));
        out[node_out_offset(node) + (size_t)(layer_k + 1) * K + lane] = nv;
    }
}

// ---------------------------------------------------------------------------
// readout: xui[i] = dot(gu[user[i]], gi[item[i]]) over 256 dims
// ---------------------------------------------------------------------------
__global__ __launch_bounds__(256) void xui_kernel(
    const int* __restrict__ user, const int* __restrict__ item,
    float* __restrict__ out)
{
    int idx = blockIdx.x * 4 + (threadIdx.x >> 6);
    if (idx >= N_QUERY) return;
    int lane = threadIdx.x & 63;
    int u  = user[idx];
    int it = item[idx];
    const float4* gu = (const float4*)(out + (size_t)N_QUERY + (size_t)u * 256);
    const float4* gi = (const float4*)(out + (size_t)N_QUERY + (size_t)NUM_ITEMS * 256
                                           + (size_t)it * 256);
    float4 a = gu[lane];
    float4 b = gi[lane];
    float d = a.x * b.x + a.y * b.y + a.z * b.z + a.w * b.w;
    #pragma unroll
    for (int off = 32; off; off >>= 1) d += __shfl_xor(d, off);
    if (lane == 0) out[idx] = d;
}

extern "C" void kernel_launch(void* const* d_in, const int* in_sizes, int n_in,
                              void* d_out, int out_size, void* d_ws, size_t ws_size,
                              hipStream_t stream)
{
    const int*   adj_rows = (const int*)  d_in[0];
    const int*   adj_cols = (const int*)  d_in[1];
    const float* adj_vals = (const float*)d_in[2];
    const float* Gu0      = (const float*)d_in[3];
    const float* Gi0      = (const float*)d_in[4];
    const float* W_gc     = (const float*)d_in[5];
    const float* b_gc     = (const float*)d_in[6];
    const float* W_bi     = (const float*)d_in[7];
    const float* b_bi     = (const float*)d_in[8];
    const int*   user     = (const int*)  d_in[9];
    const int*   item     = (const int*)  d_in[10];

    float* out = (float*)d_out;

    // workspace (~32.4 MB, <= proven-available footprint):
    //   ego   : 3.2M f  (12.8 MB)   in-place across layers
    //   side  : 3.2M f  (12.8 MB)
    //   csr_cv: 800K int2 (6.4 MB)
    //   offs  : 50001 i, cnt(=cursor): 50000 i, bsum: 256 i
    float* ego    = (float*)d_ws;
    float* side   = ego + (size_t)N_NODES * K;
    int2*  csr_cv = (int2*)(side + (size_t)N_NODES * K);
    int*   offs   = (int*)(csr_cv + N_EDGES);
    int*   cnt    = offs + N_NODES + 1;      // counts, then cursor (aliased)
    int*   bsum   = cnt + N_NODES;

    // ---- CSR build ----
    hipMemsetAsync(cnt, 0, N_NODES * sizeof(int), stream);
    count_kernel<<<(N_EDGES + 255) / 256, 256, 0, stream>>>(adj_rows, cnt);
    s1_kernel<<<NCHUNK, 256, 0, stream>>>(cnt, bsum);
    s2_kernel<<<1, 256, 0, stream>>>(bsum);
    s3_kernel<<<NCHUNK, 256, 0, stream>>>(cnt, bsum, offs, cnt);
    scatter_kernel<<<(N_EDGES + 255) / 256, 256, 0, stream>>>(
        adj_rows, adj_cols, adj_vals, cnt, csr_cv);

    // ---- init ego + layer-0 output block ----
    init_ego_kernel<<<(N_NODES * K + 255) / 256, 256, 0, stream>>>(Gu0, Gi0, ego, out);

    // ---- 3 layers: gather then transform (ego updated in place) ----
    for (int k = 0; k < 3; ++k) {
        gather_kernel<<<N_NODES / 8, 512, 0, stream>>>(offs, csr_cv, ego, side);
        transform_kernel<<<(N_NODES + 63) / 64, 256, 0, stream>>>(
            side, ego,
            W_gc + (size_t)k * K * K, b_gc + (size_t)k * K,
            W_bi + (size_t)k * K * K, b_bi + (size_t)k * K,
            out, k);
    }

    xui_kernel<<<N_QUERY / 4, 256, 0, stream>>>(user, item, out);
}